// Round 4
// baseline (113.731 us; speedup 1.0000x reference)
//
#include <hip/hip_runtime.h>

// Ball query (PointNet++ semantics), MI355X / gfx950.
// B=8, N=16384 points, M=1024 centroids, K=64 samples.
// One 64-lane wave per centroid: ordered stream compaction via 64-bit
// __ballot + popcount prefix, wave-uniform early exit at K hits.
//
// CLASSIFICATION ARITHMETIC (forensically derived, rounds 0-3):
//   - fp32 FMA diff-form, fp32 strict expanded, and f64 all gave the SAME
//     absmax=320 -> the refs (XLA dot_general + BLAS matmul recompute) share
//     an arithmetic none of those have: FMA-accumulated cross-term cp inside
//     an otherwise-strict expanded distance.
//   - cp  = fma(cz,pz, fma(cy,py, fl(cx*px)))   (K=3 dot, forward FMA chain)
//   - p2,c2 = strict mul + sequential add (separate ufunc/HLO -> no FMA)
//   - d2  = fl( fl(c2+p2) - 2*cp )              (2*cp exact: binade shift)
//   - r2  = float32(0.04)

#define BQ_N 16384
#define BQ_M 1024
#define BQ_K 64
#define BQ_R2 0.04f

__global__ __launch_bounds__(256) void BallPointQuery_kernel(
    const float* __restrict__ pts,    // [B, 3, N]
    const float* __restrict__ cents,  // [B, 3, M]
    int* __restrict__ out)            // [B, M, K] int32
{
    const int N = BQ_N, M = BQ_M, K = BQ_K;
    const int lane = threadIdx.x & 63;
    const int cid  = (blockIdx.x << 2) + (threadIdx.x >> 6);  // wave id = centroid id
    const int b = cid >> 10;          // M = 1024
    const int m = cid & (M - 1);

    const float* p = pts   + (size_t)b * 3 * N;
    const float* c = cents + (size_t)b * 3 * M;
    const float cx = c[m];
    const float cy = c[M + m];
    const float cz = c[2 * M + m];

    // c2 = (cx*cx + cy*cy) + cz*cz, strict (separate mul + reduce, no FMA).
    const float c2 = __fadd_rn(__fadd_rn(__fmul_rn(cx, cx), __fmul_rn(cy, cy)),
                               __fmul_rn(cz, cz));

    int* o = out + (size_t)cid * K;

    int count = 0;
    int first = 0;   // pad value; stays 0 if no neighbor found (matches reference)

    for (int base = 0; base < N; base += 64) {
        const int i = base + lane;
        const float px = p[i];
        const float py = p[N + i];
        const float pz = p[2 * N + i];

        // p2 strict: (px*px + py*py) + pz*pz
        const float p2 = __fadd_rn(__fadd_rn(__fmul_rn(px, px), __fmul_rn(py, py)),
                                   __fmul_rn(pz, pz));
        // cp: forward FMA chain, as BLAS sgemm / XLA dot emit for K=3.
        float cp = __fmul_rn(cx, px);
        cp = __fmaf_rn(cy, py, cp);
        cp = __fmaf_rn(cz, pz, cp);
        // d2 = (c2 + p2) - 2*cp   (2*cp exact; add and sub strict)
        const float d2 = __fsub_rn(__fadd_rn(c2, p2), __fmul_rn(2.0f, cp));

        const unsigned long long mask = __ballot(d2 <= BQ_R2);
        if (mask) {                                   // wave-uniform branch
            if (count == 0) first = base + __builtin_ctzll(mask);
            const bool hit = (mask >> lane) & 1ull;
            const int slot = count + __popcll(mask & ((1ull << lane) - 1ull));
            if (hit && slot < K) o[slot] = i;
            count += __popcll(mask);
            if (count >= K) break;                    // wave-uniform early exit
        }
    }

    // Pad slots [min(count,K), K) with the first neighbor's index (or 0).
    const int cnt = count < K ? count : K;
    if (lane >= cnt) o[lane] = first;
}

extern "C" void kernel_launch(void* const* d_in, const int* in_sizes, int n_in,
                              void* d_out, int out_size, void* d_ws, size_t ws_size,
                              hipStream_t stream) {
    const float* pts   = (const float*)d_in[0];   // [8, 3, 16384] f32
    const float* cents = (const float*)d_in[1];   // [8, 3, 1024]  f32
    int* out = (int*)d_out;                       // [8, 1024, 64] int32

    // 8 * 1024 = 8192 centroids; 4 waves (centroids) per 256-thread block.
    BallPointQuery_kernel<<<8192 / 4, 256, 0, stream>>>(pts, cents, out);
}

// Round 5
// 80.979 us; speedup vs baseline: 1.4044x; 1.4044x over previous
//
#include <hip/hip_runtime.h>

// Ball query (PointNet++ semantics), MI355X / gfx950.
// B=8, N=16384 points, M=1024 centroids, K=64 samples.
// One 64-lane wave per centroid; 256 points per iteration (4 sub-chunks of
// 64) with all 12 loads batched ahead of use for 4x memory-level
// parallelism. Ordered compaction via 64-bit __ballot + popcount prefix,
// wave-uniform early exit at K hits.
//
// CLASSIFICATION ARITHMETIC (verified passing, round 4 — do not change):
//   - cp  = fma(cz,pz, fma(cy,py, fl(cx*px)))   (K=3 dot, forward FMA chain)
//   - p2,c2 = strict mul + sequential add (no FMA)
//   - d2  = fl( fl(c2+p2) - 2*cp ),  r2 = 0.04f
// (fp32-strict / f64 variants both misclassify near-threshold points vs the
//  reference's matmul recompute — rounds 1-3 evidence.)

#define BQ_N 16384
#define BQ_M 1024
#define BQ_K 64
#define BQ_R2 0.04f

__global__ __launch_bounds__(256) void BallPointQuery_kernel(
    const float* __restrict__ pts,    // [B, 3, N]
    const float* __restrict__ cents,  // [B, 3, M]
    int* __restrict__ out)            // [B, M, K] int32
{
    const int N = BQ_N, M = BQ_M, K = BQ_K;
    const int lane = threadIdx.x & 63;
    const int cid  = (blockIdx.x << 2) + (threadIdx.x >> 6);  // wave id = centroid id
    const int b = cid >> 10;          // M = 1024
    const int m = cid & (M - 1);

    const float* p = pts   + (size_t)b * 3 * N;
    const float* c = cents + (size_t)b * 3 * M;
    const float cx = c[m];
    const float cy = c[M + m];
    const float cz = c[2 * M + m];

    // c2 = (cx*cx + cy*cy) + cz*cz, strict (no FMA).
    const float c2 = __fadd_rn(__fadd_rn(__fmul_rn(cx, cx), __fmul_rn(cy, cy)),
                               __fmul_rn(cz, cz));

    int* o = out + (size_t)cid * K;

    int count = 0;
    int first = 0;   // pad value; stays 0 if no neighbor found

    for (int base = 0; base < N && count < K; base += 256) {
        // Batch all 12 loads (4 sub-chunks x 3 coords) before any use:
        // 12 independent L2-hit chains in flight instead of 1.
        float px[4], py[4], pz[4];
        #pragma unroll
        for (int j = 0; j < 4; ++j) {
            const int i = base + 64 * j + lane;
            px[j] = p[i];
            py[j] = p[N + i];
            pz[j] = p[2 * N + i];
        }

        #pragma unroll
        for (int j = 0; j < 4; ++j) {
            // p2 strict: (px*px + py*py) + pz*pz
            const float p2 = __fadd_rn(
                __fadd_rn(__fmul_rn(px[j], px[j]), __fmul_rn(py[j], py[j])),
                __fmul_rn(pz[j], pz[j]));
            // cp: forward FMA chain (BLAS/XLA K=3 dot).
            float cp = __fmul_rn(cx, px[j]);
            cp = __fmaf_rn(cy, py[j], cp);
            cp = __fmaf_rn(cz, pz[j], cp);
            // d2 = (c2 + p2) - 2*cp
            const float d2 = __fsub_rn(__fadd_rn(c2, p2), __fmul_rn(2.0f, cp));

            const unsigned long long mask = __ballot(d2 <= BQ_R2);
            if (mask) {                                   // wave-uniform
                const int i = base + 64 * j + lane;
                if (count == 0) first = base + 64 * j + __builtin_ctzll(mask);
                const bool hit = (mask >> lane) & 1ull;
                const int slot = count + __popcll(mask & ((1ull << lane) - 1ull));
                if (hit && slot < K) o[slot] = i;
                count += __popcll(mask);
                if (count >= K) break;                    // wave-uniform
            }
        }
    }

    // Pad slots [min(count,K), K) with the first neighbor's index (or 0).
    const int cnt = count < K ? count : K;
    if (lane >= cnt) o[lane] = first;
}

extern "C" void kernel_launch(void* const* d_in, const int* in_sizes, int n_in,
                              void* d_out, int out_size, void* d_ws, size_t ws_size,
                              hipStream_t stream) {
    const float* pts   = (const float*)d_in[0];   // [8, 3, 16384] f32
    const float* cents = (const float*)d_in[1];   // [8, 3, 1024]  f32
    int* out = (int*)d_out;                       // [8, 1024, 64] int32

    // 8 * 1024 = 8192 centroids; 4 waves (centroids) per 256-thread block.
    BallPointQuery_kernel<<<8192 / 4, 256, 0, stream>>>(pts, cents, out);
}